// Round 7
// baseline (533.194 us; speedup 1.0000x reference)
//
#include <hip/hip_runtime.h>
#include <hip/hip_bf16.h>

#define NX 8192
#define NN 8192
#define DIN 512
#define DHID 32
#define DOUT 256
#define NPW (NN / 32)  // pack words per row

typedef __bf16 bf16x8 __attribute__((ext_vector_type(8)));
typedef float f32x4 __attribute__((ext_vector_type(4)));
typedef unsigned short u16x8 __attribute__((ext_vector_type(8)));

__device__ __forceinline__ unsigned short f2bf(float f) {
  __hip_bfloat16 h = __float2bfloat16(f);
  return __builtin_bit_cast(unsigned short, h);
}
__device__ __forceinline__ float bf2f(unsigned short u) {
  unsigned int v = ((unsigned int)u) << 16;
  return __builtin_bit_cast(float, v);
}
__device__ __forceinline__ f32x4 mfma16(u16x8 a, u16x8 b, f32x4 c) {
  return __builtin_amdgcn_mfma_f32_16x16x32_bf16(
      __builtin_bit_cast(bf16x8, a), __builtin_bit_cast(bf16x8, b), c, 0, 0, 0);
}
__device__ __forceinline__ u16x8 cvt8(float4 a0, float4 a1) {
  u16x8 u;
  u[0] = f2bf(a0.x); u[1] = f2bf(a0.y); u[2] = f2bf(a0.z); u[3] = f2bf(a0.w);
  u[4] = f2bf(a1.x); u[5] = f2bf(a1.y); u[6] = f2bf(a1.z); u[7] = f2bf(a1.w);
  return u;
}

// ---------------- K0: LDS-tiled transpose + bf16 convert ------------------
__global__ __launch_bounds__(256) void k_wt(
    const float* __restrict__ Wv, const float* __restrict__ Wfx,
    const float* __restrict__ Wx1, const float* __restrict__ Wn1,
    const float* __restrict__ Wx2, const float* __restrict__ Wn2,
    unsigned short* __restrict__ WvT, unsigned short* __restrict__ WfxT,
    unsigned short* __restrict__ Wx1T, unsigned short* __restrict__ Wn1T,
    unsigned short* __restrict__ Wx2T, unsigned short* __restrict__ Wn2T) {
  const float* src; unsigned short* dst; int K, C;
  switch (blockIdx.y) {
    case 0:  src = Wv;  dst = WvT;  K = DIN; C = 256; break;
    case 1:  src = Wfx; dst = WfxT; K = DIN; C = 256; break;
    case 2:  src = Wx1; dst = Wx1T; K = DIN; C = 32;  break;
    case 3:  src = Wn1; dst = Wn1T; K = DIN; C = 32;  break;
    case 4:  src = Wx2; dst = Wx2T; K = 32;  C = 32;  break;
    default: src = Wn2; dst = Wn2T; K = 32;  C = 32;  break;
  }
  int tc = C >> 5, tk = K >> 5;
  if ((int)blockIdx.x >= tc * tk) return;
  int ik = blockIdx.x / tc, ic = blockIdx.x % tc;
  __shared__ float tile[32][33];
  int t = threadIdx.x, tx = t & 31, ty0 = t >> 5;
  #pragma unroll
  for (int q = 0; q < 4; ++q) {
    int ty = ty0 + q * 8;
    tile[ty][tx] = src[(ik * 32 + ty) * C + ic * 32 + tx];
  }
  __syncthreads();
  #pragma unroll
  for (int q = 0; q < 4; ++q) {
    int ty = ty0 + q * 8;
    dst[(ic * 32 + ty) * K + ik * 32 + tx] = f2bf(tile[tx][ty]);
  }
}

// ---------------- K0b: pack adj (int32 0/1) into bitmask ------------------
__global__ __launch_bounds__(256) void k_pack(
    const int* __restrict__ adj, unsigned int* __restrict__ pack) {
  long total = (long)NX * NN;
  int gw = (blockIdx.x * 256 + threadIdx.x) >> 6;
  int lane = threadIdx.x & 63;
  int nw = (gridDim.x * 256) >> 6;
  for (long s = (long)gw * 128; s < total; s += (long)nw * 128) {
    int a0 = __builtin_nontemporal_load(&adj[s + lane]);
    int a1 = __builtin_nontemporal_load(&adj[s + 64 + lane]);
    unsigned long long b0 = __ballot(a0 > 0);
    unsigned long long b1 = __ballot(a1 > 0);
    if (lane == 0) {
      *reinterpret_cast<unsigned long long*>(&pack[s >> 5]) = b0;
      *reinterpret_cast<unsigned long long*>(&pack[(s >> 5) + 2]) = b1;
    }
  }
}

// ------- K1: merged prep GEMM: A@{Wfx|Wv} (N=256) and tanh(A@W1) (N=32) ----
__global__ __launch_bounds__(256) void k_prep(
    const float* __restrict__ x, const float* __restrict__ neigh,
    const float* __restrict__ bfx, const float* __restrict__ bv,
    const float* __restrict__ bx1, const float* __restrict__ bn1,
    const unsigned short* __restrict__ WfxT, const unsigned short* __restrict__ WvT,
    const unsigned short* __restrict__ Wx1T, const unsigned short* __restrict__ Wn1T,
    float* __restrict__ out, unsigned short* __restrict__ Vp,
    unsigned short* __restrict__ Hx, unsigned short* __restrict__ Hn) {
  int job = blockIdx.y;
  const float* A = job ? neigh : x;
  const float* bias = job ? bv : bfx;
  const float* b1 = job ? bn1 : bx1;
  const unsigned short* WT = job ? WvT : WfxT;
  const unsigned short* W1T = job ? Wn1T : Wx1T;
  unsigned short* H = job ? Hn : Hx;
  __shared__ __align__(16) char As[2][64 * 64];
  int t = threadIdx.x;
  int lane = t & 63, w = t >> 6;
  int r = lane & 15, h4 = lane >> 4;
  int bm = blockIdx.x * 64;
  f32x4 acc[4][4];
  f32x4 acch[4];
  #pragma unroll
  for (int i = 0; i < 4; ++i) {
    acch[i] = (f32x4){0.f, 0.f, 0.f, 0.f};
    #pragma unroll
    for (int j = 0; j < 4; ++j) acc[i][j] = (f32x4){0.f, 0.f, 0.f, 0.f};
  }
  int srow = t >> 2, kq = t & 3;
  const float* ap = A + (long)(bm + srow) * DIN + kq * 8;
  float4 a0 = *reinterpret_cast<const float4*>(ap);
  float4 a1 = *reinterpret_cast<const float4*>(ap + 4);
  u16x8 pbc[4], pbhc;
  #pragma unroll
  for (int nt = 0; nt < 4; ++nt)
    pbc[nt] = *reinterpret_cast<const u16x8*>(WT + (w * 64 + nt * 16 + r) * DIN + h4 * 8);
  if (w < 2)
    pbhc = *reinterpret_cast<const u16x8*>(W1T + (w * 16 + r) * DIN + h4 * 8);
  int boff = (srow * 64 + kq * 16) ^ ((srow & 3) << 4);
  int buf = 0;
  for (int kk = 0; kk < 16; ++kk) {
    u16x8 u = cvt8(a0, a1);
    *reinterpret_cast<u16x8*>(&As[buf][0] + boff) = u;
    __syncthreads();
    u16x8 pbn[4], pbhn;
    if (kk < 15) {
      a0 = *reinterpret_cast<const float4*>(ap + (kk + 1) * 32);
      a1 = *reinterpret_cast<const float4*>(ap + (kk + 1) * 32 + 4);
      #pragma unroll
      for (int nt = 0; nt < 4; ++nt)
        pbn[nt] = *reinterpret_cast<const u16x8*>(
            WT + (w * 64 + nt * 16 + r) * DIN + (kk + 1) * 32 + h4 * 8);
      if (w < 2)
        pbhn = *reinterpret_cast<const u16x8*>(
            W1T + (w * 16 + r) * DIN + (kk + 1) * 32 + h4 * 8);
    }
    #pragma unroll
    for (int mt = 0; mt < 4; ++mt) {
      int ro = mt * 16 + r;
      int aoff = (ro * 64 + h4 * 16) ^ ((ro & 3) << 4);
      u16x8 pa = *reinterpret_cast<const u16x8*>(&As[buf][0] + aoff);
      #pragma unroll
      for (int nt = 0; nt < 4; ++nt) acc[mt][nt] = mfma16(pa, pbc[nt], acc[mt][nt]);
      if (w < 2) acch[mt] = mfma16(pa, pbhc, acch[mt]);
    }
    #pragma unroll
    for (int nt = 0; nt < 4; ++nt) pbc[nt] = pbn[nt];
    pbhc = pbhn;
    buf ^= 1;
  }
  #pragma unroll
  for (int mt = 0; mt < 4; ++mt)
    #pragma unroll
    for (int nt = 0; nt < 4; ++nt) {
      int c = w * 64 + nt * 16 + r;
      #pragma unroll
      for (int j = 0; j < 4; ++j) {
        int row = bm + mt * 16 + h4 * 4 + j;
        float v = acc[mt][nt][j] + bias[c];
        if (job == 0) out[(long)row * 512 + c] = v;
        else Vp[((row >> 3) * 256 + c) * 8 + (row & 7)] = f2bf(v);
      }
    }
  if (w < 2) {
    int c = w * 16 + r;
    float bb = b1[c];
    #pragma unroll
    for (int mt = 0; mt < 4; ++mt)
      #pragma unroll
      for (int j = 0; j < 4; ++j) {
        int row = bm + mt * 16 + h4 * 4 + j;
        H[row * DHID + c] = f2bf(tanhf(acch[mt][j] + bb));
      }
  }
}

// ---------------- K2: att = H @ W2 + b2, bf16 out ------------------------
__global__ __launch_bounds__(256) void k_att(
    const unsigned short* __restrict__ Hx, const unsigned short* __restrict__ Hn,
    const float* __restrict__ bx2, const float* __restrict__ bn2,
    const unsigned short* __restrict__ Wx2T, const unsigned short* __restrict__ Wn2T,
    unsigned short* __restrict__ xatt, unsigned short* __restrict__ natt) {
  const unsigned short* H; const float* b2; const unsigned short* WT; unsigned short* att;
  if (blockIdx.y == 0) { H = Hx; b2 = bx2; WT = Wx2T; att = xatt; }
  else                 { H = Hn; b2 = bn2; WT = Wn2T; att = natt; }
  int lane = threadIdx.x & 63, w = threadIdx.x >> 6;
  int r = lane & 15, h4 = lane >> 4;
  int row = blockIdx.x * 64 + w * 16 + r;
  u16x8 af = *reinterpret_cast<const u16x8*>(H + row * DHID + h4 * 8);
  u16x8 b0 = *reinterpret_cast<const u16x8*>(WT + r * DHID + h4 * 8);
  u16x8 b1 = *reinterpret_cast<const u16x8*>(WT + (16 + r) * DHID + h4 * 8);
  f32x4 z = {0.f, 0.f, 0.f, 0.f};
  f32x4 acc0 = mfma16(af, b0, z);
  f32x4 acc1 = mfma16(af, b1, z);
  int orow = blockIdx.x * 64 + w * 16 + h4 * 4;
  #pragma unroll
  for (int j = 0; j < 4; ++j) {
    att[(orow + j) * DHID + r]      = f2bf(acc0[j] + b2[r]);
    att[(orow + j) * DHID + 16 + r] = f2bf(acc1[j] + b2[16 + r]);
  }
}

// ---------------- K3: fused flash attention over neighbors ----------------
// R6 verified structure. R7 change: XCD-aware block remap. Dispatch id fid
// round-robins over the 8 XCDs (fid%8); we remap so every block on XCD i
// works on n-chunk my = (fid&7)/(8/nc). Per-XCD L2 read set becomes one
// 1 MB Vp chunk + 128 KB natt chunk (<< 4 MB), so the ~1 GB of Vp re-reads
// (the 8 TB/s L3 wall of R4-R6) become L2 hits. If the fid->XCD heuristic
// is wrong this degrades to the current random mix (perf-neutral).
__global__ __launch_bounds__(256, 4) void k_flash(
    const unsigned int* __restrict__ pack, const unsigned short* __restrict__ xatt,
    const unsigned short* __restrict__ natt, const unsigned short* __restrict__ Vp,
    float* __restrict__ out, unsigned short* __restrict__ accP,
    float* __restrict__ lP, int nc) {
  __shared__ unsigned short P[2][32 * 72];  // double-buffered 32x64 (+pad)
  __shared__ float lpart[4][32];
  int t = threadIdx.x;
  int lane = t & 63, w = t >> 6;
  int r = lane & 15, h4 = lane >> 4;
  // --- XCD-aware remap (bijective for nc in {1,2,4}) ---
  int fid = blockIdx.y * gridDim.x + blockIdx.x;
  int g = 8 / nc;            // XCDs per n-chunk
  int m8 = fid & 7;
  int my = m8 / g;           // n-chunk for this XCD
  int mx = (fid >> 3) * g + (m8 % g);
  int rb = mx * 32;
  int L = NN / nc;
  int base = my * L;
  int NIT = L / 64;
  u16x8 qf0 = *reinterpret_cast<const u16x8*>(xatt + (rb + r) * DHID + h4 * 8);
  u16x8 qf1 = *reinterpret_cast<const u16x8*>(xatt + (rb + 16 + r) * DHID + h4 * 8);
  f32x4 o[2][4];
  #pragma unroll
  for (int i = 0; i < 2; ++i)
    #pragma unroll
    for (int j = 0; j < 4; ++j) o[i][j] = (f32x4){0.f, 0.f, 0.f, 0.f};
  float psum[8];
  #pragma unroll
  for (int i = 0; i < 8; ++i) psum[i] = 0.f;
  // mask bit for this lane's P column: n = n0 + w*16 + r
  unsigned int bmask = 1u << (((w & 1) << 4) + r);
  int wofs = w >> 1;  // word offset within the iter's 2-word span
  // 2-deep pipelines: A = iter i (ready), B = iter i+1 (in flight / ready)
  unsigned int mA[8], mB[8];
  u16x8 kfA, kfB;
  #pragma unroll
  for (int rt = 0; rt < 2; ++rt)
    #pragma unroll
    for (int j = 0; j < 4; ++j) {
      long prow = (long)(rb + rt * 16 + h4 * 4 + j) * NPW;
      mA[rt * 4 + j] = __builtin_nontemporal_load(&pack[prow + (base >> 5) + wofs]);
      mB[rt * 4 + j] = __builtin_nontemporal_load(&pack[prow + ((base + 64) >> 5) + wofs]);
    }
  kfA = *reinterpret_cast<const u16x8*>(natt + (base + w * 16 + r) * DHID + h4 * 8);
  kfB = *reinterpret_cast<const u16x8*>(natt + (base + 64 + w * 16 + r) * DHID + h4 * 8);
  int buf = 0;
  int lastn = base + L - 64;
  for (int it = 0; it < NIT; ++it) {
    int n0 = base + it * 64;
    // ---- QK + mask/exp + P-write (uses A-slot registers, zero-wait) ----
    f32x4 z = {0.f, 0.f, 0.f, 0.f};
    f32x4 s0 = mfma16(qf0, kfA, z);
    f32x4 s1 = mfma16(qf1, kfA, z);
    unsigned short* Pb = &P[buf][0];
    #pragma unroll
    for (int rt = 0; rt < 2; ++rt) {
      f32x4 s = rt ? s1 : s0;
      #pragma unroll
      for (int j = 0; j < 4; ++j) {
        float sv = s[j];
        float lr = fminf(fmaxf(sv, 0.01f * sv), 60.f);  // leaky_relu + guard
        float p = (mA[rt * 4 + j] & bmask) ? __expf(lr) : 0.f;
        psum[rt * 4 + j] += p;
        Pb[(rt * 16 + h4 * 4 + j) * 72 + w * 16 + r] = f2bf(p);
      }
    }
    __syncthreads();  // P[buf] visible; drains (aged) in-flight loads
    // ---- post-barrier: rotate pipeline, issue loads for iter it+2 ----
    #pragma unroll
    for (int q = 0; q < 8; ++q) mA[q] = mB[q];
    kfA = kfB;
    int n2 = n0 + 128 <= lastn ? n0 + 128 : lastn;  // clamped (dup harmless)
    #pragma unroll
    for (int rt = 0; rt < 2; ++rt)
      #pragma unroll
      for (int j = 0; j < 4; ++j)
        mB[rt * 4 + j] = __builtin_nontemporal_load(
            &pack[(long)(rb + rt * 16 + h4 * 4 + j) * NPW + (n2 >> 5) + wofs]);
    kfB = *reinterpret_cast<const u16x8*>(natt + (n2 + w * 16 + r) * DHID + h4 * 8);
    // ---- PV phase: ds_reads + Vp loads then MFMA cluster ----
    u16x8 pa[2][2], vf[2][4];
    #pragma unroll
    for (int kb = 0; kb < 2; ++kb) {
      pa[kb][0] = *reinterpret_cast<const u16x8*>(Pb + r * 72 + kb * 32 + h4 * 8);
      pa[kb][1] = *reinterpret_cast<const u16x8*>(Pb + (16 + r) * 72 + kb * 32 + h4 * 8);
    }
    #pragma unroll
    for (int kb = 0; kb < 2; ++kb) {
      long vbase = ((long)((n0 + kb * 32) >> 3) + h4) * (DOUT * 8);
      #pragma unroll
      for (int nt = 0; nt < 4; ++nt)
        vf[kb][nt] = *reinterpret_cast<const u16x8*>(Vp + vbase + (w * 64 + nt * 16 + r) * 8);
    }
    #pragma unroll
    for (int kb = 0; kb < 2; ++kb)
      #pragma unroll
      for (int nt = 0; nt < 4; ++nt) {
        o[0][nt] = mfma16(pa[kb][0], vf[kb][nt], o[0][nt]);
        o[1][nt] = mfma16(pa[kb][1], vf[kb][nt], o[1][nt]);
      }
    buf ^= 1;  // old buf reads complete before its next overwrite (2 barriers away)
  }
  // row-sum: reduce psum over the 16 r-lanes (h4 groups independent)
  #pragma unroll
  for (int q = 1; q < 16; q <<= 1)
    #pragma unroll
    for (int i = 0; i < 8; ++i) psum[i] += __shfl_xor(psum[i], q);
  if (r == 0) {
    #pragma unroll
    for (int rt = 0; rt < 2; ++rt)
      #pragma unroll
      for (int j = 0; j < 4; ++j)
        lpart[w][rt * 16 + h4 * 4 + j] = psum[rt * 4 + j];
  }
  __syncthreads();
  if (nc == 1) {
    #pragma unroll
    for (int rt = 0; rt < 2; ++rt)
      #pragma unroll
      for (int nt = 0; nt < 4; ++nt) {
        int c = w * 64 + nt * 16 + r;
        #pragma unroll
        for (int j = 0; j < 4; ++j) {
          int rl = rt * 16 + h4 * 4 + j;
          float l = lpart[0][rl] + lpart[1][rl] + lpart[2][rl] + lpart[3][rl];
          out[(long)(rb + rl) * 512 + 256 + c] = o[rt][nt][j] / l;
        }
      }
  } else {
    long cb = (long)my * NX;
    #pragma unroll
    for (int rt = 0; rt < 2; ++rt)
      #pragma unroll
      for (int nt = 0; nt < 4; ++nt) {
        int c = w * 64 + nt * 16 + r;
        #pragma unroll
        for (int j = 0; j < 4; ++j) {
          int rl = rt * 16 + h4 * 4 + j;
          accP[(cb + rb + rl) * DOUT + c] = f2bf(o[rt][nt][j]);
        }
      }
    if (t < 32)
      lP[my * NX + rb + t] =
          lpart[0][t] + lpart[1][t] + lpart[2][t] + lpart[3][t];
  }
}

// ---------------- K4: combine neighbor-chunk partials ---------------------
__global__ __launch_bounds__(256) void k_combine(
    const unsigned short* __restrict__ accP, const float* __restrict__ lP,
    float* __restrict__ out, int nc) {
  long idx = (long)blockIdx.x * 256 + threadIdx.x;  // over NX*DOUT
  int row = (int)(idx >> 8), c = (int)(idx & 255);
  float s = 0.f, l = 0.f;
  for (int q = 0; q < nc; ++q) {
    s += bf2f(accP[(long)q * NX * DOUT + idx]);
    l += lP[q * NX + row];
  }
  out[(long)row * 512 + 256 + c] = s / l;
}

extern "C" void kernel_launch(void* const* d_in, const int* in_sizes, int n_in,
                              void* d_out, int out_size, void* d_ws, size_t ws_size,
                              hipStream_t stream) {
  const float* x    = (const float*)d_in[0];
  const float* neigh= (const float*)d_in[1];
  const int*   adj  = (const int*)d_in[2];
  const float* Wx1  = (const float*)d_in[3];
  const float* bx1  = (const float*)d_in[4];
  const float* Wx2  = (const float*)d_in[5];
  const float* bx2  = (const float*)d_in[6];
  const float* Wn1  = (const float*)d_in[7];
  const float* bn1  = (const float*)d_in[8];
  const float* Wn2  = (const float*)d_in[9];
  const float* bn2  = (const float*)d_in[10];
  const float* Wv   = (const float*)d_in[11];
  const float* bv   = (const float*)d_in[12];
  const float* Wfx  = (const float*)d_in[13];
  const float* bfx  = (const float*)d_in[14];
  float* out = (float*)d_out;
  char* ws = (char*)d_ws;

  unsigned short* xatt = (unsigned short*)(ws + 0);
  unsigned short* natt = (unsigned short*)(ws + 524288);
  unsigned short* Hx   = (unsigned short*)(ws + 1048576);
  unsigned short* Hn   = (unsigned short*)(ws + 1572864);
  unsigned short* Vp   = (unsigned short*)(ws + 2097152);
  unsigned short* WvT  = (unsigned short*)(ws + 6291456);
  unsigned short* WfxT = (unsigned short*)(ws + 6553600);
  unsigned short* Wx1T = (unsigned short*)(ws + 6815744);
  unsigned short* Wn1T = (unsigned short*)(ws + 6848512);
  unsigned short* Wx2T = (unsigned short*)(ws + 6881280);
  unsigned short* Wn2T = (unsigned short*)(ws + 6883328);
  unsigned int*   packb = (unsigned int*)(ws + 7340032);   // 8 MB bitmask

  const size_t OFF_ACC = 16777216;                  // 16 MB
  const size_t CHUNK_ACC = (size_t)NX * DOUT * 2;   // 4 MB bf16 per chunk
  size_t need4 = OFF_ACC + 4 * (CHUNK_ACC + (size_t)NX * 4);
  size_t need2 = OFF_ACC + 2 * (CHUNK_ACC + (size_t)NX * 4);
  int nc = (ws_size >= need4) ? 4 : (ws_size >= need2) ? 2 : 1;
  unsigned short* accP = (unsigned short*)(ws + OFF_ACC);
  float* lP = (float*)(ws + OFF_ACC + (size_t)nc * CHUNK_ACC);

  k_wt<<<dim3(128, 6), 256, 0, stream>>>(Wv, Wfx, Wx1, Wn1, Wx2, Wn2,
                                         WvT, WfxT, Wx1T, Wn1T, Wx2T, Wn2T);
  k_pack<<<dim3(2048), 256, 0, stream>>>(adj, packb);
  k_prep<<<dim3(128, 2), 256, 0, stream>>>(x, neigh, bfx, bv, bx1, bn1,
                                           WfxT, WvT, Wx1T, Wn1T, out, Vp, Hx, Hn);
  k_att<<<dim3(128, 2), 256, 0, stream>>>(Hx, Hn, bx2, bn2, Wx2T, Wn2T, xatt, natt);
  k_flash<<<dim3(256, nc), 256, 0, stream>>>(packb, xatt, natt, Vp, out, accP, lP, nc);
  if (nc > 1)
    k_combine<<<dim3(NX * DOUT / 256), 256, 0, stream>>>(accP, lP, out, nc);
}

// Round 8
// 488.537 us; speedup vs baseline: 1.0914x; 1.0914x over previous
//
#include <hip/hip_runtime.h>
#include <hip/hip_bf16.h>

#define NX 8192
#define NN 8192
#define DIN 512
#define DHID 32
#define DOUT 256

typedef __bf16 bf16x8 __attribute__((ext_vector_type(8)));
typedef float f32x4 __attribute__((ext_vector_type(4)));
typedef unsigned short u16x8 __attribute__((ext_vector_type(8)));

__device__ __forceinline__ unsigned short f2bf(float f) {
  __hip_bfloat16 h = __float2bfloat16(f);
  return __builtin_bit_cast(unsigned short, h);
}
__device__ __forceinline__ float bf2f(unsigned short u) {
  unsigned int v = ((unsigned int)u) << 16;
  return __builtin_bit_cast(float, v);
}
__device__ __forceinline__ f32x4 mfma16(u16x8 a, u16x8 b, f32x4 c) {
  return __builtin_amdgcn_mfma_f32_16x16x32_bf16(
      __builtin_bit_cast(bf16x8, a), __builtin_bit_cast(bf16x8, b), c, 0, 0, 0);
}
__device__ __forceinline__ u16x8 cvt8(float4 a0, float4 a1) {
  u16x8 u;
  u[0] = f2bf(a0.x); u[1] = f2bf(a0.y); u[2] = f2bf(a0.z); u[3] = f2bf(a0.w);
  u[4] = f2bf(a1.x); u[5] = f2bf(a1.y); u[6] = f2bf(a1.z); u[7] = f2bf(a1.w);
  return u;
}

// ---------------- K0: LDS-tiled transpose + bf16 convert ------------------
__global__ __launch_bounds__(256) void k_wt(
    const float* __restrict__ Wv, const float* __restrict__ Wfx,
    const float* __restrict__ Wx1, const float* __restrict__ Wn1,
    const float* __restrict__ Wx2, const float* __restrict__ Wn2,
    unsigned short* __restrict__ WvT, unsigned short* __restrict__ WfxT,
    unsigned short* __restrict__ Wx1T, unsigned short* __restrict__ Wn1T,
    unsigned short* __restrict__ Wx2T, unsigned short* __restrict__ Wn2T) {
  const float* src; unsigned short* dst; int K, C;
  switch (blockIdx.y) {
    case 0:  src = Wv;  dst = WvT;  K = DIN; C = 256; break;
    case 1:  src = Wfx; dst = WfxT; K = DIN; C = 256; break;
    case 2:  src = Wx1; dst = Wx1T; K = DIN; C = 32;  break;
    case 3:  src = Wn1; dst = Wn1T; K = DIN; C = 32;  break;
    case 4:  src = Wx2; dst = Wx2T; K = 32;  C = 32;  break;
    default: src = Wn2; dst = Wn2T; K = 32;  C = 32;  break;
  }
  int tc = C >> 5, tk = K >> 5;
  if ((int)blockIdx.x >= tc * tk) return;
  int ik = blockIdx.x / tc, ic = blockIdx.x % tc;
  __shared__ float tile[32][33];
  int t = threadIdx.x, tx = t & 31, ty0 = t >> 5;
  #pragma unroll
  for (int q = 0; q < 4; ++q) {
    int ty = ty0 + q * 8;
    tile[ty][tx] = src[(ik * 32 + ty) * C + ic * 32 + tx];
  }
  __syncthreads();
  #pragma unroll
  for (int q = 0; q < 4; ++q) {
    int ty = ty0 + q * 8;
    dst[(ic * 32 + ty) * K + ik * 32 + tx] = f2bf(tile[tx][ty]);
  }
}

// ------- K1: merged prep GEMM: A@{Wfx|Wv} (N=256) and tanh(A@W1) (N=32) ----
__global__ __launch_bounds__(256) void k_prep(
    const float* __restrict__ x, const float* __restrict__ neigh,
    const float* __restrict__ bfx, const float* __restrict__ bv,
    const float* __restrict__ bx1, const float* __restrict__ bn1,
    const unsigned short* __restrict__ WfxT, const unsigned short* __restrict__ WvT,
    const unsigned short* __restrict__ Wx1T, const unsigned short* __restrict__ Wn1T,
    float* __restrict__ out, unsigned short* __restrict__ Vp,
    unsigned short* __restrict__ Hx, unsigned short* __restrict__ Hn) {
  int job = blockIdx.y;
  const float* A = job ? neigh : x;
  const float* bias = job ? bv : bfx;
  const float* b1 = job ? bn1 : bx1;
  const unsigned short* WT = job ? WvT : WfxT;
  const unsigned short* W1T = job ? Wn1T : Wx1T;
  unsigned short* H = job ? Hn : Hx;
  __shared__ __align__(16) char As[2][64 * 64];
  int t = threadIdx.x;
  int lane = t & 63, w = t >> 6;
  int r = lane & 15, h4 = lane >> 4;
  int bm = blockIdx.x * 64;
  f32x4 acc[4][4];
  f32x4 acch[4];
  #pragma unroll
  for (int i = 0; i < 4; ++i) {
    acch[i] = (f32x4){0.f, 0.f, 0.f, 0.f};
    #pragma unroll
    for (int j = 0; j < 4; ++j) acc[i][j] = (f32x4){0.f, 0.f, 0.f, 0.f};
  }
  int srow = t >> 2, kq = t & 3;
  const float* ap = A + (long)(bm + srow) * DIN + kq * 8;
  float4 a0 = *reinterpret_cast<const float4*>(ap);
  float4 a1 = *reinterpret_cast<const float4*>(ap + 4);
  u16x8 pbc[4], pbhc;
  #pragma unroll
  for (int nt = 0; nt < 4; ++nt)
    pbc[nt] = *reinterpret_cast<const u16x8*>(WT + (w * 64 + nt * 16 + r) * DIN + h4 * 8);
  if (w < 2)
    pbhc = *reinterpret_cast<const u16x8*>(W1T + (w * 16 + r) * DIN + h4 * 8);
  int boff = (srow * 64 + kq * 16) ^ ((srow & 3) << 4);
  int buf = 0;
  for (int kk = 0; kk < 16; ++kk) {
    u16x8 u = cvt8(a0, a1);
    *reinterpret_cast<u16x8*>(&As[buf][0] + boff) = u;
    __syncthreads();
    u16x8 pbn[4], pbhn;
    if (kk < 15) {
      a0 = *reinterpret_cast<const float4*>(ap + (kk + 1) * 32);
      a1 = *reinterpret_cast<const float4*>(ap + (kk + 1) * 32 + 4);
      #pragma unroll
      for (int nt = 0; nt < 4; ++nt)
        pbn[nt] = *reinterpret_cast<const u16x8*>(
            WT + (w * 64 + nt * 16 + r) * DIN + (kk + 1) * 32 + h4 * 8);
      if (w < 2)
        pbhn = *reinterpret_cast<const u16x8*>(
            W1T + (w * 16 + r) * DIN + (kk + 1) * 32 + h4 * 8);
    }
    #pragma unroll
    for (int mt = 0; mt < 4; ++mt) {
      int ro = mt * 16 + r;
      int aoff = (ro * 64 + h4 * 16) ^ ((ro & 3) << 4);
      u16x8 pa = *reinterpret_cast<const u16x8*>(&As[buf][0] + aoff);
      #pragma unroll
      for (int nt = 0; nt < 4; ++nt) acc[mt][nt] = mfma16(pa, pbc[nt], acc[mt][nt]);
      if (w < 2) acch[mt] = mfma16(pa, pbhc, acch[mt]);
    }
    #pragma unroll
    for (int nt = 0; nt < 4; ++nt) pbc[nt] = pbn[nt];
    pbhc = pbhn;
    buf ^= 1;
  }
  #pragma unroll
  for (int mt = 0; mt < 4; ++mt)
    #pragma unroll
    for (int nt = 0; nt < 4; ++nt) {
      int c = w * 64 + nt * 16 + r;
      #pragma unroll
      for (int j = 0; j < 4; ++j) {
        int row = bm + mt * 16 + h4 * 4 + j;
        float v = acc[mt][nt][j] + bias[c];
        if (job == 0) out[(long)row * 512 + c] = v;
        else Vp[((row >> 3) * 256 + c) * 8 + (row & 7)] = f2bf(v);
      }
    }
  if (w < 2) {
    int c = w * 16 + r;
    float bb = b1[c];
    #pragma unroll
    for (int mt = 0; mt < 4; ++mt)
      #pragma unroll
      for (int j = 0; j < 4; ++j) {
        int row = bm + mt * 16 + h4 * 4 + j;
        H[row * DHID + c] = f2bf(tanhf(acch[mt][j] + bb));
      }
  }
}

// ---------------- K2: att = H @ W2 + b2, bf16 out ------------------------
__global__ __launch_bounds__(256) void k_att(
    const unsigned short* __restrict__ Hx, const unsigned short* __restrict__ Hn,
    const float* __restrict__ bx2, const float* __restrict__ bn2,
    const unsigned short* __restrict__ Wx2T, const unsigned short* __restrict__ Wn2T,
    unsigned short* __restrict__ xatt, unsigned short* __restrict__ natt) {
  const unsigned short* H; const float* b2; const unsigned short* WT; unsigned short* att;
  if (blockIdx.y == 0) { H = Hx; b2 = bx2; WT = Wx2T; att = xatt; }
  else                 { H = Hn; b2 = bn2; WT = Wn2T; att = natt; }
  int lane = threadIdx.x & 63, w = threadIdx.x >> 6;
  int r = lane & 15, h4 = lane >> 4;
  int row = blockIdx.x * 64 + w * 16 + r;
  u16x8 af = *reinterpret_cast<const u16x8*>(H + row * DHID + h4 * 8);
  u16x8 b0 = *reinterpret_cast<const u16x8*>(WT + r * DHID + h4 * 8);
  u16x8 b1 = *reinterpret_cast<const u16x8*>(WT + (16 + r) * DHID + h4 * 8);
  f32x4 z = {0.f, 0.f, 0.f, 0.f};
  f32x4 acc0 = mfma16(af, b0, z);
  f32x4 acc1 = mfma16(af, b1, z);
  int orow = blockIdx.x * 64 + w * 16 + h4 * 4;
  #pragma unroll
  for (int j = 0; j < 4; ++j) {
    att[(orow + j) * DHID + r]      = f2bf(acc0[j] + b2[r]);
    att[(orow + j) * DHID + 16 + r] = f2bf(acc1[j] + b2[16 + r]);
  }
}

// ---------------- K3: fused flash attention, BQ=128 / KVBLK=32 ------------
// 1024 threads = 16 waves; wave w: row-tile rt=w>>1 (16 rows), n-half ns=w&1.
// Per iter (32 neighbors): QK (1 MFMA) -> exp/mask -> P[pb] write -> barrier
// -> {rotate adj/kf regs, issue it+2 loads, issue V slab(it+2) global load}
// -> PV (8 MFMA) from P[pb] + V_lds[vb] -> ds_write V_lds[vb^1] <- staged
// slab(it+1) regs (T14 issue-early/write-late; aged one full iter).
// V tile is a contiguous 16 KB slab of K-packed Vp -> linear LDS copy; the
// 16 waves share it, cutting V global traffic 4x vs per-wave reads (1 GB ->
// 256 MB) and per-CU V bytes/iter 128 KB -> 32 KB. adj read directly (NT).
// All cross-wave reuse separated by >=1 full __syncthreads (R4-proven epochs).
__global__ __launch_bounds__(1024, 2) void k_flash(
    const int* __restrict__ adj, const unsigned short* __restrict__ xatt,
    const unsigned short* __restrict__ natt, const unsigned short* __restrict__ Vp,
    float* __restrict__ out, unsigned short* __restrict__ accP,
    float* __restrict__ lP, int nc) {
  __shared__ unsigned short P[2][128 * 40];     // 32 cols + 8 pad
  __shared__ __align__(16) unsigned short Vl[2][4 * 256 * 8];  // 16 KB each
  __shared__ float lpart[16][16];
  int t = threadIdx.x;
  int lane = t & 63, w = t >> 6;
  int r = lane & 15, h4 = lane >> 4;
  int rt = w >> 1, ns = w & 1;
  // XCD-grouped bijective remap (grid 64*nc, nc in {1,2,4})
  int fid = blockIdx.y * gridDim.x + blockIdx.x;
  int g = 8 / nc;
  int m8 = fid & 7;
  int my = m8 / g;
  int mx = (fid >> 3) * g + (m8 % g);
  int rb = mx * 128;
  int L = NN / nc;
  int base = my * L;
  int NIT = L / 32;
  int lastn = base + L - 32;
  u16x8 qf = *reinterpret_cast<const u16x8*>(xatt + (rb + rt * 16 + r) * DHID + h4 * 8);
  f32x4 o[8];
  #pragma unroll
  for (int i = 0; i < 8; ++i) o[i] = (f32x4){0.f, 0.f, 0.f, 0.f};
  float psum[4] = {0.f, 0.f, 0.f, 0.f};
  // 2-deep adj / kf pipelines
  int adjA[4], adjB[4];
  u16x8 kfA, kfB;
  #pragma unroll
  for (int j = 0; j < 4; ++j) {
    long ro = (long)(rb + rt * 16 + h4 * 4 + j) * NN + ns * 16 + r;
    adjA[j] = __builtin_nontemporal_load(&adj[ro + base]);
    adjB[j] = __builtin_nontemporal_load(&adj[ro + base + 32]);
  }
  kfA = *reinterpret_cast<const u16x8*>(natt + (base + ns * 16 + r) * DHID + h4 * 8);
  kfB = *reinterpret_cast<const u16x8*>(natt + (base + 32 + ns * 16 + r) * DHID + h4 * 8);
  // V staging: slab(it) = Vp + (base+it*32)*256 u16, 16 KB contiguous
  {
    u16x8 v0 = *reinterpret_cast<const u16x8*>(Vp + (long)base * 256 + t * 8);
    *reinterpret_cast<u16x8*>(&Vl[0][0] + t * 8) = v0;
  }
  u16x8 vregA = *reinterpret_cast<const u16x8*>(Vp + (long)(base + 32) * 256 + t * 8);
  __syncthreads();
  int pb = 0, vb = 0;
  for (int it = 0; it < NIT; ++it) {
    int n0 = base + it * 32;
    // ---- QK + mask/exp + P write (register operands, zero-wait) ----
    f32x4 z = {0.f, 0.f, 0.f, 0.f};
    f32x4 s = mfma16(qf, kfA, z);
    unsigned short* Pb = &P[pb][0];
    #pragma unroll
    for (int j = 0; j < 4; ++j) {
      float sv = s[j];
      float lr = fminf(fmaxf(sv, 0.01f * sv), 60.f);  // leaky_relu + guard
      float p = (adjA[j] > 0) ? __expf(lr) : 0.f;
      psum[j] += p;
      Pb[(rt * 16 + h4 * 4 + j) * 40 + ns * 16 + r] = f2bf(p);
    }
    __syncthreads();  // P[pb] + V_lds[vb] (written last iter) visible
    // ---- post-barrier: rotate pipelines, issue it+2 loads ----
    #pragma unroll
    for (int j = 0; j < 4; ++j) adjA[j] = adjB[j];
    kfA = kfB;
    int nn = n0 + 64 <= lastn ? n0 + 64 : lastn;  // clamped (dup harmless)
    #pragma unroll
    for (int j = 0; j < 4; ++j)
      adjB[j] = __builtin_nontemporal_load(
          &adj[(long)(rb + rt * 16 + h4 * 4 + j) * NN + nn + ns * 16 + r]);
    kfB = *reinterpret_cast<const u16x8*>(natt + (nn + ns * 16 + r) * DHID + h4 * 8);
    u16x8 vregB = *reinterpret_cast<const u16x8*>(Vp + (long)nn * 256 + t * 8);
    // ---- PV: P[pb] x V_lds[vb] -> o ----
    u16x8 pa = *reinterpret_cast<const u16x8*>(&P[pb][0] + (rt * 16 + r) * 40 + h4 * 8);
    #pragma unroll
    for (int ct = 0; ct < 8; ++ct) {
      u16x8 vf = *reinterpret_cast<const u16x8*>(
          &Vl[vb][0] + (h4 * 256 + ns * 128 + ct * 16 + r) * 8);
      o[ct] = mfma16(pa, vf, o[ct]);
    }
    // ---- write staged slab(it+1) into the other V buffer ----
    *reinterpret_cast<u16x8*>(&Vl[vb ^ 1][0] + t * 8) = vregA;
    vregA = vregB;
    pb ^= 1; vb ^= 1;
  }
  // ---- psum reduce over the 16 r-lanes ----
  #pragma unroll
  for (int q = 1; q < 16; q <<= 1)
    #pragma unroll
    for (int j = 0; j < 4; ++j) psum[j] += __shfl_xor(psum[j], q);
  if (r == 0) {
    #pragma unroll
    for (int j = 0; j < 4; ++j) lpart[w][h4 * 4 + j] = psum[j];
  }
  __syncthreads();
  int cb = ns * 128;
  if (nc == 1) {
    #pragma unroll
    for (int ct = 0; ct < 8; ++ct) {
      int c = cb + ct * 16 + r;
      #pragma unroll
      for (int j = 0; j < 4; ++j) {
        int rl = rt * 16 + h4 * 4 + j;
        float l = lpart[2 * rt][h4 * 4 + j] + lpart[2 * rt + 1][h4 * 4 + j];
        out[(long)(rb + rl) * 512 + 256 + c] = o[ct][j] / l;
      }
    }
  } else {
    long cbase = (long)my * NX;
    #pragma unroll
    for (int ct = 0; ct < 8; ++ct) {
      int c = cb + ct * 16 + r;
      #pragma unroll
      for (int j = 0; j < 4; ++j) {
        int rl = rt * 16 + h4 * 4 + j;
        accP[(cbase + rb + rl) * DOUT + c] = f2bf(o[ct][j]);
      }
    }
    if (t < 128)
      lP[my * NX + rb + t] =
          lpart[2 * (t >> 4)][t & 15] + lpart[2 * (t >> 4) + 1][t & 15];
  }
}

// ---------------- K4: combine neighbor-chunk partials ---------------------
__global__ __launch_bounds__(256) void k_combine(
    const unsigned short* __restrict__ accP, const float* __restrict__ lP,
    float* __restrict__ out, int nc) {
  long idx = (long)blockIdx.x * 256 + threadIdx.x;  // over NX*DOUT
  int row = (int)(idx >> 8), c = (int)(idx & 255);
  float s = 0.f, l = 0.f;
  for (int q = 0; q < nc; ++q) {
    s += bf2f(accP[(long)q * NX * DOUT + idx]);
    l += lP[q * NX + row];
  }
  out[(long)row * 512 + 256 + c] = s / l;
}

extern "C" void kernel_launch(void* const* d_in, const int* in_sizes, int n_in,
                              void* d_out, int out_size, void* d_ws, size_t ws_size,
                              hipStream_t stream) {
  const float* x    = (const float*)d_in[0];
  const float* neigh= (const float*)d_in[1];
  const int*   adj  = (const int*)d_in[2];
  const float* Wx1  = (const float*)d_in[3];
  const float* bx1  = (const float*)d_in[4];
  const float* Wx2  = (const float*)d_in[5];
  const float* bx2  = (const float*)d_in[6];
  const float* Wn1  = (const float*)d_in[7];
  const float* bn1  = (const float*)d_in[8];
  const float* Wn2  = (const float*)d_in[9];
  const float* bn2  = (const float*)d_in[10];
  const float* Wv   = (const float*)d_in[11];
  const float* bv   = (const float*)d_in[12];
  const float* Wfx  = (const float*)d_in[13];
  const float* bfx  = (const float*)d_in[14];
  float* out = (float*)d_out;
  char* ws = (char*)d_ws;

  unsigned short* xatt = (unsigned short*)(ws + 0);
  unsigned short* natt = (unsigned short*)(ws + 524288);
  unsigned short* Hx   = (unsigned short*)(ws + 1048576);
  unsigned short* Hn   = (unsigned short*)(ws + 1572864);
  unsigned short* Vp   = (unsigned short*)(ws + 2097152);
  unsigned short* WvT  = (unsigned short*)(ws + 6291456);
  unsigned short* WfxT = (unsigned short*)(ws + 6553600);
  unsigned short* Wx1T = (unsigned short*)(ws + 6815744);
  unsigned short* Wn1T = (unsigned short*)(ws + 6848512);
  unsigned short* Wx2T = (unsigned short*)(ws + 6881280);
  unsigned short* Wn2T = (unsigned short*)(ws + 6883328);

  const size_t OFF_ACC = 16777216;                  // 16 MB
  const size_t CHUNK_ACC = (size_t)NX * DOUT * 2;   // 4 MB bf16 per chunk
  size_t need4 = OFF_ACC + 4 * (CHUNK_ACC + (size_t)NX * 4);
  size_t need2 = OFF_ACC + 2 * (CHUNK_ACC + (size_t)NX * 4);
  int nc = (ws_size >= need4) ? 4 : (ws_size >= need2) ? 2 : 1;
  unsigned short* accP = (unsigned short*)(ws + OFF_ACC);
  float* lP = (float*)(ws + OFF_ACC + (size_t)nc * CHUNK_ACC);

  k_wt<<<dim3(128, 6), 256, 0, stream>>>(Wv, Wfx, Wx1, Wn1, Wx2, Wn2,
                                         WvT, WfxT, Wx1T, Wn1T, Wx2T, Wn2T);
  k_prep<<<dim3(128, 2), 256, 0, stream>>>(x, neigh, bfx, bv, bx1, bn1,
                                           WfxT, WvT, Wx1T, Wn1T, out, Vp, Hx, Hn);
  k_att<<<dim3(128, 2), 256, 0, stream>>>(Hx, Hn, bx2, bn2, Wx2T, Wn2T, xatt, natt);
  k_flash<<<dim3(64, nc), 1024, 0, stream>>>(adj, xatt, natt, Vp, out, accP, lP, nc);
  if (nc > 1)
    k_combine<<<dim3(NX * DOUT / 256), 256, 0, stream>>>(accP, lP, out, nc);
}

// Round 9
// 461.904 us; speedup vs baseline: 1.1543x; 1.0577x over previous
//
#include <hip/hip_runtime.h>
#include <hip/hip_bf16.h>

#define NX 8192
#define NN 8192
#define DIN 512
#define DHID 32
#define DOUT 256

typedef __bf16 bf16x8 __attribute__((ext_vector_type(8)));
typedef float f32x4 __attribute__((ext_vector_type(4)));
typedef unsigned short u16x8 __attribute__((ext_vector_type(8)));

__device__ __forceinline__ unsigned short f2bf(float f) {
  __hip_bfloat16 h = __float2bfloat16(f);
  return __builtin_bit_cast(unsigned short, h);
}
__device__ __forceinline__ float bf2f(unsigned short u) {
  unsigned int v = ((unsigned int)u) << 16;
  return __builtin_bit_cast(float, v);
}
__device__ __forceinline__ f32x4 mfma16(u16x8 a, u16x8 b, f32x4 c) {
  return __builtin_amdgcn_mfma_f32_16x16x32_bf16(
      __builtin_bit_cast(bf16x8, a), __builtin_bit_cast(bf16x8, b), c, 0, 0, 0);
}
__device__ __forceinline__ u16x8 cvt8(float4 a0, float4 a1) {
  u16x8 u;
  u[0] = f2bf(a0.x); u[1] = f2bf(a0.y); u[2] = f2bf(a0.z); u[3] = f2bf(a0.w);
  u[4] = f2bf(a1.x); u[5] = f2bf(a1.y); u[6] = f2bf(a1.z); u[7] = f2bf(a1.w);
  return u;
}

// ---------------- K0: LDS-tiled transpose + bf16 convert ------------------
__global__ __launch_bounds__(256) void k_wt(
    const float* __restrict__ Wv, const float* __restrict__ Wfx,
    const float* __restrict__ Wx1, const float* __restrict__ Wn1,
    const float* __restrict__ Wx2, const float* __restrict__ Wn2,
    unsigned short* __restrict__ WvT, unsigned short* __restrict__ WfxT,
    unsigned short* __restrict__ Wx1T, unsigned short* __restrict__ Wn1T,
    unsigned short* __restrict__ Wx2T, unsigned short* __restrict__ Wn2T) {
  const float* src; unsigned short* dst; int K, C;
  switch (blockIdx.y) {
    case 0:  src = Wv;  dst = WvT;  K = DIN; C = 256; break;
    case 1:  src = Wfx; dst = WfxT; K = DIN; C = 256; break;
    case 2:  src = Wx1; dst = Wx1T; K = DIN; C = 32;  break;
    case 3:  src = Wn1; dst = Wn1T; K = DIN; C = 32;  break;
    case 4:  src = Wx2; dst = Wx2T; K = 32;  C = 32;  break;
    default: src = Wn2; dst = Wn2T; K = 32;  C = 32;  break;
  }
  int tc = C >> 5, tk = K >> 5;
  if ((int)blockIdx.x >= tc * tk) return;
  int ik = blockIdx.x / tc, ic = blockIdx.x % tc;
  __shared__ float tile[32][33];
  int t = threadIdx.x, tx = t & 31, ty0 = t >> 5;
  #pragma unroll
  for (int q = 0; q < 4; ++q) {
    int ty = ty0 + q * 8;
    tile[ty][tx] = src[(ik * 32 + ty) * C + ic * 32 + tx];
  }
  __syncthreads();
  #pragma unroll
  for (int q = 0; q < 4; ++q) {
    int ty = ty0 + q * 8;
    dst[(ic * 32 + ty) * K + ik * 32 + tx] = f2bf(tile[tx][ty]);
  }
}

// ------- K1: merged prep GEMM: A@{Wfx|Wv} (N=256) and tanh(A@W1) (N=32) ----
__global__ __launch_bounds__(256) void k_prep(
    const float* __restrict__ x, const float* __restrict__ neigh,
    const float* __restrict__ bfx, const float* __restrict__ bv,
    const float* __restrict__ bx1, const float* __restrict__ bn1,
    const unsigned short* __restrict__ WfxT, const unsigned short* __restrict__ WvT,
    const unsigned short* __restrict__ Wx1T, const unsigned short* __restrict__ Wn1T,
    float* __restrict__ out, unsigned short* __restrict__ Vp,
    unsigned short* __restrict__ Hx, unsigned short* __restrict__ Hn) {
  int job = blockIdx.y;
  const float* A = job ? neigh : x;
  const float* bias = job ? bv : bfx;
  const float* b1 = job ? bn1 : bx1;
  const unsigned short* WT = job ? WvT : WfxT;
  const unsigned short* W1T = job ? Wn1T : Wx1T;
  unsigned short* H = job ? Hn : Hx;
  __shared__ __align__(16) char As[2][64 * 64];
  int t = threadIdx.x;
  int lane = t & 63, w = t >> 6;
  int r = lane & 15, h4 = lane >> 4;
  int bm = blockIdx.x * 64;
  f32x4 acc[4][4];
  f32x4 acch[4];
  #pragma unroll
  for (int i = 0; i < 4; ++i) {
    acch[i] = (f32x4){0.f, 0.f, 0.f, 0.f};
    #pragma unroll
    for (int j = 0; j < 4; ++j) acc[i][j] = (f32x4){0.f, 0.f, 0.f, 0.f};
  }
  int srow = t >> 2, kq = t & 3;
  const float* ap = A + (long)(bm + srow) * DIN + kq * 8;
  float4 a0 = *reinterpret_cast<const float4*>(ap);
  float4 a1 = *reinterpret_cast<const float4*>(ap + 4);
  u16x8 pbc[4], pbhc;
  #pragma unroll
  for (int nt = 0; nt < 4; ++nt)
    pbc[nt] = *reinterpret_cast<const u16x8*>(WT + (w * 64 + nt * 16 + r) * DIN + h4 * 8);
  if (w < 2)
    pbhc = *reinterpret_cast<const u16x8*>(W1T + (w * 16 + r) * DIN + h4 * 8);
  int boff = (srow * 64 + kq * 16) ^ ((srow & 3) << 4);
  int buf = 0;
  for (int kk = 0; kk < 16; ++kk) {
    u16x8 u = cvt8(a0, a1);
    *reinterpret_cast<u16x8*>(&As[buf][0] + boff) = u;
    __syncthreads();
    u16x8 pbn[4], pbhn;
    if (kk < 15) {
      a0 = *reinterpret_cast<const float4*>(ap + (kk + 1) * 32);
      a1 = *reinterpret_cast<const float4*>(ap + (kk + 1) * 32 + 4);
      #pragma unroll
      for (int nt = 0; nt < 4; ++nt)
        pbn[nt] = *reinterpret_cast<const u16x8*>(
            WT + (w * 64 + nt * 16 + r) * DIN + (kk + 1) * 32 + h4 * 8);
      if (w < 2)
        pbhn = *reinterpret_cast<const u16x8*>(
            W1T + (w * 16 + r) * DIN + (kk + 1) * 32 + h4 * 8);
    }
    #pragma unroll
    for (int mt = 0; mt < 4; ++mt) {
      int ro = mt * 16 + r;
      int aoff = (ro * 64 + h4 * 16) ^ ((ro & 3) << 4);
      u16x8 pa = *reinterpret_cast<const u16x8*>(&As[buf][0] + aoff);
      #pragma unroll
      for (int nt = 0; nt < 4; ++nt) acc[mt][nt] = mfma16(pa, pbc[nt], acc[mt][nt]);
      if (w < 2) acch[mt] = mfma16(pa, pbhc, acch[mt]);
    }
    #pragma unroll
    for (int nt = 0; nt < 4; ++nt) pbc[nt] = pbn[nt];
    pbhc = pbhn;
    buf ^= 1;
  }
  #pragma unroll
  for (int mt = 0; mt < 4; ++mt)
    #pragma unroll
    for (int nt = 0; nt < 4; ++nt) {
      int c = w * 64 + nt * 16 + r;
      #pragma unroll
      for (int j = 0; j < 4; ++j) {
        int row = bm + mt * 16 + h4 * 4 + j;
        float v = acc[mt][nt][j] + bias[c];
        if (job == 0) out[(long)row * 512 + c] = v;
        else Vp[((row >> 3) * 256 + c) * 8 + (row & 7)] = f2bf(v);
      }
    }
  if (w < 2) {
    int c = w * 16 + r;
    float bb = b1[c];
    #pragma unroll
    for (int mt = 0; mt < 4; ++mt)
      #pragma unroll
      for (int j = 0; j < 4; ++j) {
        int row = bm + mt * 16 + h4 * 4 + j;
        H[row * DHID + c] = f2bf(tanhf(acch[mt][j] + bb));
      }
  }
}

// ---------------- K2: att = H @ W2 + b2, bf16 out ------------------------
__global__ __launch_bounds__(256) void k_att(
    const unsigned short* __restrict__ Hx, const unsigned short* __restrict__ Hn,
    const float* __restrict__ bx2, const float* __restrict__ bn2,
    const unsigned short* __restrict__ Wx2T, const unsigned short* __restrict__ Wn2T,
    unsigned short* __restrict__ xatt, unsigned short* __restrict__ natt) {
  const unsigned short* H; const float* b2; const unsigned short* WT; unsigned short* att;
  if (blockIdx.y == 0) { H = Hx; b2 = bx2; WT = Wx2T; att = xatt; }
  else                 { H = Hn; b2 = bn2; WT = Wn2T; att = natt; }
  int lane = threadIdx.x & 63, w = threadIdx.x >> 6;
  int r = lane & 15, h4 = lane >> 4;
  int row = blockIdx.x * 64 + w * 16 + r;
  u16x8 af = *reinterpret_cast<const u16x8*>(H + row * DHID + h4 * 8);
  u16x8 b0 = *reinterpret_cast<const u16x8*>(WT + r * DHID + h4 * 8);
  u16x8 b1 = *reinterpret_cast<const u16x8*>(WT + (16 + r) * DHID + h4 * 8);
  f32x4 z = {0.f, 0.f, 0.f, 0.f};
  f32x4 acc0 = mfma16(af, b0, z);
  f32x4 acc1 = mfma16(af, b1, z);
  int orow = blockIdx.x * 64 + w * 16 + h4 * 4;
  #pragma unroll
  for (int j = 0; j < 4; ++j) {
    att[(orow + j) * DHID + r]      = f2bf(acc0[j] + b2[r]);
    att[(orow + j) * DHID + 16 + r] = f2bf(acc1[j] + b2[16 + r]);
  }
}

// ---------------- K3: flash attention, per-wave-independent P -------------
// 512 threads = 8 waves; wave w owns q-rows [rb+w*16, +16) x ALL 256 c-cols.
// Swapped QK: s = mfma(K,Q) -> lane(h4,r) holds S^T[n=4*h4+j][q=r]. Mask/exp
// at producer lane (adj int4 per lane, coalesced), P staged in a PER-WAVE
// LDS scratch (producer==consumer wave -> NO barrier; compiler lgkmcnt
// orders it). PV reads P as A-frag [q=r][n=8*h4+i] + shared V from LDS.
// The ONLY cross-wave coupling is V staging: 64-n chunks (32 KB) double-
// buffered, ONE barrier per 2 iters, reg-staged with issue-early/write-late
// (V regs aged a full chunk ~2300 cyc). adj/kf 2-deep reg pipelines.
__global__ __launch_bounds__(512, 2) void k_flash(
    const int* __restrict__ adj, const unsigned short* __restrict__ xatt,
    const unsigned short* __restrict__ natt, const unsigned short* __restrict__ Vp,
    float* __restrict__ out, unsigned short* __restrict__ accP,
    float* __restrict__ lP, int nc) {
  __shared__ __align__(16) unsigned short Vl[2][64 * 256];  // 2 x 32 KB
  __shared__ __align__(16) unsigned short Ps[8][16 * 40];   // per-wave P scratch
  int t = threadIdx.x;
  int lane = t & 63, w = t >> 6;
  int r = lane & 15, h4 = lane >> 4;
  // XCD-grouped bijective remap (grid 64 x nc)
  int fid = blockIdx.y * gridDim.x + blockIdx.x;
  int g = 8 / nc;
  int m8 = fid & 7;
  int my = m8 / g;
  int mx = (fid >> 3) * g + (m8 % g);
  int rb = mx * 128;
  int L = NN / nc;
  int base = my * L;
  int NCH = L / 64;                // chunks of 64 neighbors (2 iters each)
  int qrow = rb + w * 16;
  u16x8 qf = *reinterpret_cast<const u16x8*>(xatt + (long)(qrow + r) * DHID + h4 * 8);
  f32x4 o[16];
  #pragma unroll
  for (int i = 0; i < 16; ++i) o[i] = (f32x4){0.f, 0.f, 0.f, 0.f};
  float psum = 0.f;
  const int* ap = adj + (long)(qrow + r) * NN + h4 * 4;  // + n0 + half*16
  // ---- prologue ----
  u16x8 vs[4], vs2[4];
  #pragma unroll
  for (int q = 0; q < 4; ++q)
    vs[q] = *reinterpret_cast<const u16x8*>(Vp + (long)base * 256 + (q * 512 + t) * 8);
  int4 ajA[2], ajB[2];
  u16x8 kfA[2], kfB[2];
  #pragma unroll
  for (int h = 0; h < 2; ++h) {
    ajA[h] = *reinterpret_cast<const int4*>(ap + base + h * 16);
    ajB[h] = *reinterpret_cast<const int4*>(ap + base + 32 + h * 16);
    kfA[h] = *reinterpret_cast<const u16x8*>(natt + (long)(base + h * 16 + r) * DHID + h4 * 8);
    kfB[h] = *reinterpret_cast<const u16x8*>(natt + (long)(base + 32 + h * 16 + r) * DHID + h4 * 8);
  }
  #pragma unroll
  for (int q = 0; q < 4; ++q)
    *reinterpret_cast<u16x8*>(&Vl[0][(q * 512 + t) * 8]) = vs[q];
  #pragma unroll
  for (int q = 0; q < 4; ++q)
    vs[q] = *reinterpret_cast<const u16x8*>(
        Vp + (long)(base + 64) * 256 + (q * 512 + t) * 8);
  __syncthreads();
  int vb = 0;
  int lastit = 2 * NCH - 1;
  for (int c = 0; c < NCH; ++c) {
    // issue chunk c+2 global loads (consumed next chunk; aged >= 1 chunk)
    int c2 = c + 2 < NCH ? c + 2 : NCH - 1;
    #pragma unroll
    for (int q = 0; q < 4; ++q)
      vs2[q] = *reinterpret_cast<const u16x8*>(
          Vp + (long)(base + c2 * 64) * 256 + (q * 512 + t) * 8);
    // write chunk c+1 (regs aged 1 chunk) into the idle buffer
    #pragma unroll
    for (int q = 0; q < 4; ++q)
      *reinterpret_cast<u16x8*>(&Vl[vb ^ 1][(q * 512 + t) * 8]) = vs[q];
    unsigned short* Pw = &Ps[w][0];
    const unsigned short* Vb = &Vl[vb][0];
    #pragma unroll
    for (int s2 = 0; s2 < 2; ++s2) {
      int it = 2 * c + s2;
      int itp = it + 2 <= lastit ? it + 2 : lastit;
      int np = base + itp * 32;
      // ---- QK (swapped) + mask/exp + per-wave P write ----
      #pragma unroll
      for (int h = 0; h < 2; ++h) {
        f32x4 z = {0.f, 0.f, 0.f, 0.f};
        f32x4 s = mfma16(kfA[h], qf, z);
        int am[4] = {ajA[h].x, ajA[h].y, ajA[h].z, ajA[h].w};
        #pragma unroll
        for (int j = 0; j < 4; ++j) {
          float sv = s[j];
          float lr = fminf(fmaxf(sv, 0.01f * sv), 60.f);  // leaky_relu + guard
          float p = (am[j] > 0) ? __expf(lr) : 0.f;
          psum += p;
          Pw[r * 40 + h * 16 + h4 * 4 + j] = f2bf(p);
        }
      }
      // rotate pipelines; issue it+2 loads
      #pragma unroll
      for (int h = 0; h < 2; ++h) {
        ajA[h] = ajB[h];
        kfA[h] = kfB[h];
        ajB[h] = *reinterpret_cast<const int4*>(ap + np + h * 16);
        kfB[h] = *reinterpret_cast<const u16x8*>(
            natt + (long)(np + h * 16 + r) * DHID + h4 * 8);
      }
      // ---- PV: A = P[q=r][n=8*h4+i] (same-wave scratch), B = shared V ----
      u16x8 pa = *reinterpret_cast<const u16x8*>(Pw + r * 40 + h4 * 8);
      #pragma unroll
      for (int ct = 0; ct < 16; ++ct) {
        u16x8 vf = *reinterpret_cast<const u16x8*>(
            Vb + ((s2 * 4 + h4) * 256 + ct * 16 + r) * 8);
        o[ct] = mfma16(pa, vf, o[ct]);
      }
    }
    #pragma unroll
    for (int q = 0; q < 4; ++q) vs[q] = vs2[q];
    __syncthreads();  // V[vb^1] writes done; all reads of V[vb] done
    vb ^= 1;
  }
  // ---- epilogue: denominators fully in-register ----
  psum += __shfl_xor(psum, 16);
  psum += __shfl_xor(psum, 32);  // every lane: full lsum for q = r
  float lq[4];
  #pragma unroll
  for (int j = 0; j < 4; ++j) lq[j] = __shfl(psum, h4 * 4 + j);
  if (nc == 1) {
    #pragma unroll
    for (int ct = 0; ct < 16; ++ct) {
      int cc = ct * 16 + r;
      #pragma unroll
      for (int j = 0; j < 4; ++j)
        out[(long)(qrow + h4 * 4 + j) * 512 + 256 + cc] = o[ct][j] / lq[j];
    }
  } else {
    long cb = (long)my * NX;
    #pragma unroll
    for (int ct = 0; ct < 16; ++ct) {
      int cc = ct * 16 + r;
      #pragma unroll
      for (int j = 0; j < 4; ++j)
        accP[(cb + qrow + h4 * 4 + j) * DOUT + cc] = f2bf(o[ct][j]);
    }
    if (h4 == 0) lP[my * NX + qrow + r] = psum;
  }
}

// ---------------- K4: combine neighbor-chunk partials ---------------------
__global__ __launch_bounds__(256) void k_combine(
    const unsigned short* __restrict__ accP, const float* __restrict__ lP,
    float* __restrict__ out, int nc) {
  long idx = (long)blockIdx.x * 256 + threadIdx.x;  // over NX*DOUT
  int row = (int)(idx >> 8), c = (int)(idx & 255);
  float s = 0.f, l = 0.f;
  for (int q = 0; q < nc; ++q) {
    s += bf2f(accP[(long)q * NX * DOUT + idx]);
    l += lP[q * NX + row];
  }
  out[(long)row * 512 + 256 + c] = s / l;
}

extern "C" void kernel_launch(void* const* d_in, const int* in_sizes, int n_in,
                              void* d_out, int out_size, void* d_ws, size_t ws_size,
                              hipStream_t stream) {
  const float* x    = (const float*)d_in[0];
  const float* neigh= (const float*)d_in[1];
  const int*   adj  = (const int*)d_in[2];
  const float* Wx1  = (const float*)d_in[3];
  const float* bx1  = (const float*)d_in[4];
  const float* Wx2  = (const float*)d_in[5];
  const float* bx2  = (const float*)d_in[6];
  const float* Wn1  = (const float*)d_in[7];
  const float* bn1  = (const float*)d_in[8];
  const float* Wn2  = (const float*)d_in[9];
  const float* bn2  = (const float*)d_in[10];
  const float* Wv   = (const float*)d_in[11];
  const float* bv   = (const float*)d_in[12];
  const float* Wfx  = (const float*)d_in[13];
  const float* bfx  = (const float*)d_in[14];
  float* out = (float*)d_out;
  char* ws = (char*)d_ws;

  unsigned short* xatt = (unsigned short*)(ws + 0);
  unsigned short* natt = (unsigned short*)(ws + 524288);
  unsigned short* Hx   = (unsigned short*)(ws + 1048576);
  unsigned short* Hn   = (unsigned short*)(ws + 1572864);
  unsigned short* Vp   = (unsigned short*)(ws + 2097152);
  unsigned short* WvT  = (unsigned short*)(ws + 6291456);
  unsigned short* WfxT = (unsigned short*)(ws + 6553600);
  unsigned short* Wx1T = (unsigned short*)(ws + 6815744);
  unsigned short* Wn1T = (unsigned short*)(ws + 6848512);
  unsigned short* Wx2T = (unsigned short*)(ws + 6881280);
  unsigned short* Wn2T = (unsigned short*)(ws + 6883328);

  const size_t OFF_ACC = 16777216;                  // 16 MB
  const size_t CHUNK_ACC = (size_t)NX * DOUT * 2;   // 4 MB bf16 per chunk
  size_t need4 = OFF_ACC + 4 * (CHUNK_ACC + (size_t)NX * 4);
  size_t need2 = OFF_ACC + 2 * (CHUNK_ACC + (size_t)NX * 4);
  int nc = (ws_size >= need4) ? 4 : (ws_size >= need2) ? 2 : 1;
  unsigned short* accP = (unsigned short*)(ws + OFF_ACC);
  float* lP = (float*)(ws + OFF_ACC + (size_t)nc * CHUNK_ACC);

  k_wt<<<dim3(128, 6), 256, 0, stream>>>(Wv, Wfx, Wx1, Wn1, Wx2, Wn2,
                                         WvT, WfxT, Wx1T, Wn1T, Wx2T, Wn2T);
  k_prep<<<dim3(128, 2), 256, 0, stream>>>(x, neigh, bfx, bv, bx1, bn1,
                                           WfxT, WvT, Wx1T, Wn1T, out, Vp, Hx, Hn);
  k_att<<<dim3(128, 2), 256, 0, stream>>>(Hx, Hn, bx2, bn2, Wx2T, Wn2T, xatt, natt);
  k_flash<<<dim3(64, nc), 512, 0, stream>>>(adj, xatt, natt, Vp, out, accP, lP, nc);
  if (nc > 1)
    k_combine<<<dim3(NX * DOUT / 256), 256, 0, stream>>>(accP, lP, out, nc);
}